// Round 1
// baseline (419.133 us; speedup 1.0000x reference)
//
#include <hip/hip_runtime.h>
#include <math.h>

#define DEG_EPS 1e-12f
#define LN_EPS  1e-5f

// ---------------------------------------------------------------------------
// 1) deg[i] = 1.0 (self loop) ; then atomic-add edge weights by row
// ---------------------------------------------------------------------------
__global__ __launch_bounds__(256) void k_init_deg(float* __restrict__ deg, int N) {
    int i = blockIdx.x * blockDim.x + threadIdx.x;
    if (i < N) deg[i] = 1.0f;
}

__global__ __launch_bounds__(256) void k_scatter_deg(const int* __restrict__ rows,
                                                     const float* __restrict__ ew,
                                                     float* __restrict__ deg, int E) {
    int e = blockIdx.x * blockDim.x + threadIdx.x;
    if (e < E) unsafeAtomicAdd(&deg[rows[e]], ew[e]);
}

// ---------------------------------------------------------------------------
// 2) h init = self-loop contribution: x[i]*dis_i^2 = x[i]/(deg+eps)
//    (h lives in d_out; deterministic, no atomics)
// ---------------------------------------------------------------------------
__global__ __launch_bounds__(256) void k_init_h(const float4* __restrict__ x4,
                                                const float* __restrict__ deg,
                                                float4* __restrict__ h4, int N) {
    int idx = blockIdx.x * blockDim.x + threadIdx.x;   // N*16 float4s
    if (idx < N * 16) {
        int i = idx >> 4;
        float inv = 1.0f / (deg[i] + DEG_EPS);
        float4 v = x4[idx];
        v.x *= inv; v.y *= inv; v.z *= inv; v.w *= inv;
        h4[idx] = v;
    }
}

// ---------------------------------------------------------------------------
// 3) SpMM scatter: one wave per edge, lane = feature.
//    h[row][lane] += x[col][lane] * ew * rsqrt(deg[row]) * rsqrt(deg[col])
// ---------------------------------------------------------------------------
__global__ __launch_bounds__(256) void k_spmm(const int* __restrict__ rows,
                                              const int* __restrict__ cols,
                                              const float* __restrict__ ew,
                                              const float* __restrict__ deg,
                                              const float* __restrict__ x,
                                              float* __restrict__ h, int E) {
    int t = blockIdx.x * blockDim.x + threadIdx.x;
    int e = t >> 6;
    if (e >= E) return;
    int lane = t & 63;
    int r = rows[e], c = cols[e];
    float nw = ew[e] * rsqrtf(deg[r] + DEG_EPS) * rsqrtf(deg[c] + DEG_EPS);
    unsafeAtomicAdd(&h[r * 64 + lane], x[c * 64 + lane] * nw);
}

// ---------------------------------------------------------------------------
// 4) Epilogue: y = gelu(h@W^T + b); LN(y)*gamma+beta + x
//    Lane-per-node: each lane holds one node's 64 h values in VGPRs.
//    W[j*64+k] is wave-uniform -> scalar/broadcast loads; matvec = pure VALU.
//    LDS pitch 65 breaks all bank conflicts on the two transposes.
// ---------------------------------------------------------------------------
__global__ __launch_bounds__(256) void k_epilogue(
    const float4* __restrict__ x4, const float* __restrict__ W,
    const float* __restrict__ bias, const float4* __restrict__ g4,
    const float4* __restrict__ bt4, float* __restrict__ h /* in/out = d_out */,
    int N)
{
    __shared__ float slab_s[4][64 * 65];
    __shared__ float mean_s[4][64];
    __shared__ float rstd_s[4][64];
    const int wv   = threadIdx.x >> 6;
    const int lane = threadIdx.x & 63;
    float* slab = slab_s[wv];
    const int i0 = (blockIdx.x * 4 + wv) * 64;
    const int nvalid = (i0 < N) ? min(64, N - i0) : 0;
    const float4* h4 = (const float4*)h;
    float4* out4 = (float4*)h;

    // phase 1: coalesced load of tile (<=64 nodes x 64 feats) into padded LDS
#pragma unroll
    for (int it = 0; it < 16; ++it) {
        int idx = it * 64 + lane;
        int n = idx >> 4, k4 = idx & 15;
        if (n < nvalid) {
            float4 v = h4[(i0 + n) * 16 + k4];
            int base = n * 65 + k4 * 4;
            slab[base] = v.x; slab[base + 1] = v.y;
            slab[base + 2] = v.z; slab[base + 3] = v.w;
        }
    }
    __syncthreads();

    // phase 2: lane <- its node's h row (conflict-free: bank=(lane+k)%32)
    float hr[64];
#pragma unroll
    for (int k = 0; k < 64; ++k) hr[k] = slab[lane * 65 + k];
    __syncthreads();

    float sum = 0.f, sumsq = 0.f;
    for (int j = 0; j < 64; ++j) {          // j uniform across wave
        float a = bias[j];                  // scalar load
#pragma unroll
        for (int k = 0; k < 64; ++k)
            a = fmaf(hr[k], W[j * 64 + k], a);   // uniform W address
        // exact gelu: 0.5*a*(1+erf(a/sqrt(2)))
        a = 0.5f * a * (1.0f + erff(a * 0.70710678118654752f));
        sum += a; sumsq += a * a;
        slab[lane * 65 + j] = a;            // conflict-free write-back
    }
    float mean = sum * (1.0f / 64.0f);
    float var  = fmaxf(sumsq * (1.0f / 64.0f) - mean * mean, 0.0f);
    mean_s[wv][lane] = mean;
    rstd_s[wv][lane] = rsqrtf(var + LN_EPS);
    __syncthreads();

    // phase 3: transpose-store with gamma/beta + residual (coalesced)
#pragma unroll
    for (int it = 0; it < 16; ++it) {
        int idx = it * 64 + lane;
        int n = idx >> 4, k4 = idx & 15;
        if (n < nvalid) {
            float m = mean_s[wv][n], r = rstd_s[wv][n];
            float4 gg = g4[k4], bb = bt4[k4];
            float4 xx = x4[(i0 + n) * 16 + k4];
            int base = n * 65 + k4 * 4;
            float4 o;
            o.x = (slab[base]     - m) * r * gg.x + bb.x + xx.x;
            o.y = (slab[base + 1] - m) * r * gg.y + bb.y + xx.y;
            o.z = (slab[base + 2] - m) * r * gg.z + bb.z + xx.z;
            o.w = (slab[base + 3] - m) * r * gg.w + bb.w + xx.w;
            out4[(i0 + n) * 16 + k4] = o;
        }
    }
}

// ---------------------------------------------------------------------------
extern "C" void kernel_launch(void* const* d_in, const int* in_sizes, int n_in,
                              void* d_out, int out_size, void* d_ws, size_t ws_size,
                              hipStream_t stream) {
    const float* x   = (const float*)d_in[0];
    const int*   ei  = (const int*)  d_in[1];   // [2,E] flat: rows then cols
    const float* ew  = (const float*)d_in[2];
    const float* W   = (const float*)d_in[3];
    const float* b   = (const float*)d_in[4];
    const float* g   = (const float*)d_in[5];
    const float* bt  = (const float*)d_in[6];
    float* out = (float*)d_out;

    const int N = in_sizes[0] / 64;
    const int E = in_sizes[1] / 2;
    const int* rows = ei;
    const int* cols = ei + E;

    float* deg = (float*)d_ws;   // N floats

    // 1) degrees
    k_init_deg<<<(N + 255) / 256, 256, 0, stream>>>(deg, N);
    k_scatter_deg<<<(E + 255) / 256, 256, 0, stream>>>(rows, ew, deg, E);

    // 2) h init (self loops) into d_out
    k_init_h<<<(N * 16 + 255) / 256, 256, 0, stream>>>(
        (const float4*)x, deg, (float4*)out, N);

    // 3) SpMM scatter (64 lanes per edge)
    long total = (long)E * 64;
    k_spmm<<<(int)((total + 255) / 256), 256, 0, stream>>>(
        rows, cols, ew, deg, x, out, E);

    // 4) epilogue: matvec + gelu + layernorm + residual, in-place on d_out
    int tiles = (N + 63) / 64;
    k_epilogue<<<(tiles + 3) / 4, 256, 0, stream>>>(
        (const float4*)x, W, b, (const float4*)g, (const float4*)bt, out, N);
}

// Round 2
// 337.056 us; speedup vs baseline: 1.2435x; 1.2435x over previous
//
#include <hip/hip_runtime.h>
#include <math.h>

#define DEG_EPS 1e-12f
#define LN_EPS  1e-5f

// ---------------------------------------------------------------------------
// ws layout (bytes):
//   meta    : E * 8   (int2 {col, bitcast(nw)})          offset 0
//   deg/dis : N * 4   (deg, overwritten in-place by dis = rsqrt(deg+eps))
//   counts  : N * 4   (edge counts, then reused as fill cursor)
//   rowptr  : (N+1)*4
//   bsums   : NB * 4
//   boffs   : NB * 4
// ---------------------------------------------------------------------------

// 1) deg = 1.0 (self loop), counts = 0
__global__ __launch_bounds__(256) void k_init(float* __restrict__ deg,
                                              int* __restrict__ counts, int N) {
    int i = blockIdx.x * blockDim.x + threadIdx.x;
    if (i < N) { deg[i] = 1.0f; counts[i] = 0; }
}

// 2) deg[row] += ew ; counts[row]++
__global__ __launch_bounds__(256) void k_deg_count(const int* __restrict__ rows,
                                                   const float* __restrict__ ew,
                                                   float* __restrict__ deg,
                                                   int* __restrict__ counts, int E) {
    int e = blockIdx.x * blockDim.x + threadIdx.x;
    if (e < E) {
        int r = rows[e];
        unsafeAtomicAdd(&deg[r], ew[e]);
        atomicAdd(&counts[r], 1);
    }
}

// 3a) per-block (1024 counts) reduction -> bsums
__global__ __launch_bounds__(256) void k_scan1(const int* __restrict__ counts,
                                               int* __restrict__ bsums, int N) {
    __shared__ int sc[256];
    int t = threadIdx.x, b = blockIdx.x;
    int base = b * 1024 + t * 4;
    int s = 0;
#pragma unroll
    for (int k = 0; k < 4; ++k) { int i = base + k; if (i < N) s += counts[i]; }
    sc[t] = s; __syncthreads();
    for (int off = 128; off > 0; off >>= 1) {
        if (t < off) sc[t] += sc[t + off];
        __syncthreads();
    }
    if (t == 0) bsums[b] = sc[0];
}

// 3b) serial exclusive scan of block sums (NB ~ 98)
__global__ void k_scan2(const int* __restrict__ bsums, int* __restrict__ boffs,
                        int* __restrict__ rowptr, int NB, int N) {
    if (threadIdx.x == 0 && blockIdx.x == 0) {
        int run = 0;
        for (int b = 0; b < NB; ++b) { boffs[b] = run; run += bsums[b]; }
        rowptr[N] = run;   // == E
    }
}

// 3c) block scan -> rowptr (exclusive); also cursor=0 and dis = rsqrt(deg+eps)
__global__ __launch_bounds__(256) void k_scan3(const int* __restrict__ counts,
                                               const int* __restrict__ boffs,
                                               int* __restrict__ rowptr,
                                               int* __restrict__ cursor,
                                               float* __restrict__ deg_to_dis, int N) {
    __shared__ int sc[256];
    int t = threadIdx.x, b = blockIdx.x;
    int base = b * 1024 + t * 4;
    int c[4]; int s = 0;
#pragma unroll
    for (int k = 0; k < 4; ++k) {
        int i = base + k;
        c[k] = (i < N) ? counts[i] : 0;
        s += c[k];
    }
    sc[t] = s; __syncthreads();
    int mySum = s;
    for (int off = 1; off < 256; off <<= 1) {
        int v = (t >= off) ? sc[t - off] : 0;
        __syncthreads();
        sc[t] += v;
        __syncthreads();
    }
    int run = sc[t] - mySum + boffs[b];
#pragma unroll
    for (int k = 0; k < 4; ++k) {
        int i = base + k;
        if (i < N) {
            rowptr[i] = run;
            cursor[i] = 0;
            deg_to_dis[i] = rsqrtf(deg_to_dis[i] + DEG_EPS);  // deg -> dis in place
        }
        run += c[k];
    }
}

// 4) fill CSR: meta[slot] = {col, nw}
__global__ __launch_bounds__(256) void k_fill(const int* __restrict__ rows,
                                              const int* __restrict__ cols,
                                              const float* __restrict__ ew,
                                              const float* __restrict__ dis,
                                              const int* __restrict__ rowptr,
                                              int* __restrict__ cursor,
                                              int2* __restrict__ meta, int E) {
    int e = blockIdx.x * blockDim.x + threadIdx.x;
    if (e < E) {
        int r = rows[e], c = cols[e];
        float nw = ew[e] * dis[r] * dis[c];
        int slot = rowptr[r] + atomicAdd(&cursor[r], 1);
        meta[slot] = make_int2(c, __float_as_int(nw));
    }
}

// 5) SpMM gather: one wave per row, lane = feature. No atomics.
__global__ __launch_bounds__(256) void k_spmm_csr(const int* __restrict__ rowptr,
                                                  const int2* __restrict__ meta,
                                                  const float* __restrict__ dis,
                                                  const float* __restrict__ x,
                                                  float* __restrict__ h, int N) {
    int t = blockIdx.x * blockDim.x + threadIdx.x;
    int row = t >> 6;
    if (row >= N) return;
    int lane = t & 63;

    float s = dis[row];                       // wave-uniform
    float acc = x[row * 64 + lane] * (s * s); // self loop: x / (deg+eps)

    int start = rowptr[row], end = rowptr[row + 1];
    for (int base = start; base < end; base += 64) {
        int rem = end - base;
        int cnt = rem < 64 ? rem : 64;
        int2 m = make_int2(0, 0);
        if (lane < rem) m = meta[base + lane];   // 64 edges in one coalesced load
        int j = 0;
        for (; j + 4 <= cnt; j += 4) {
            int   c0 = __shfl(m.x, j + 0, 64);
            float w0 = __int_as_float(__shfl(m.y, j + 0, 64));
            int   c1 = __shfl(m.x, j + 1, 64);
            float w1 = __int_as_float(__shfl(m.y, j + 1, 64));
            int   c2 = __shfl(m.x, j + 2, 64);
            float w2 = __int_as_float(__shfl(m.y, j + 2, 64));
            int   c3 = __shfl(m.x, j + 3, 64);
            float w3 = __int_as_float(__shfl(m.y, j + 3, 64));
            float v0 = x[c0 * 64 + lane];
            float v1 = x[c1 * 64 + lane];
            float v2 = x[c2 * 64 + lane];
            float v3 = x[c3 * 64 + lane];
            acc = fmaf(v0, w0, acc);
            acc = fmaf(v1, w1, acc);
            acc = fmaf(v2, w2, acc);
            acc = fmaf(v3, w3, acc);
        }
        for (; j < cnt; ++j) {
            int   c = __shfl(m.x, j, 64);
            float w = __int_as_float(__shfl(m.y, j, 64));
            acc = fmaf(x[c * 64 + lane], w, acc);
        }
    }
    h[row * 64 + lane] = acc;
}

// ---------------------------------------------------------------------------
// 6) Epilogue: y = gelu(h@W^T + b); LN(y)*gamma+beta + x  (in-place on d_out)
// ---------------------------------------------------------------------------
__global__ __launch_bounds__(256) void k_epilogue(
    const float4* __restrict__ x4, const float* __restrict__ W,
    const float* __restrict__ bias, const float4* __restrict__ g4,
    const float4* __restrict__ bt4, float* __restrict__ h, int N)
{
    __shared__ float slab_s[4][64 * 65];
    __shared__ float mean_s[4][64];
    __shared__ float rstd_s[4][64];
    const int wv   = threadIdx.x >> 6;
    const int lane = threadIdx.x & 63;
    float* slab = slab_s[wv];
    const int i0 = (blockIdx.x * 4 + wv) * 64;
    const int nvalid = (i0 < N) ? min(64, N - i0) : 0;
    const float4* h4 = (const float4*)h;
    float4* out4 = (float4*)h;

#pragma unroll
    for (int it = 0; it < 16; ++it) {
        int idx = it * 64 + lane;
        int n = idx >> 4, k4 = idx & 15;
        if (n < nvalid) {
            float4 v = h4[(i0 + n) * 16 + k4];
            int base = n * 65 + k4 * 4;
            slab[base] = v.x; slab[base + 1] = v.y;
            slab[base + 2] = v.z; slab[base + 3] = v.w;
        }
    }
    __syncthreads();

    float hr[64];
#pragma unroll
    for (int k = 0; k < 64; ++k) hr[k] = slab[lane * 65 + k];
    __syncthreads();

    float sum = 0.f, sumsq = 0.f;
    for (int j = 0; j < 64; ++j) {
        float a = bias[j];
#pragma unroll
        for (int k = 0; k < 64; ++k)
            a = fmaf(hr[k], W[j * 64 + k], a);
        a = 0.5f * a * (1.0f + erff(a * 0.70710678118654752f));
        sum += a; sumsq += a * a;
        slab[lane * 65 + j] = a;
    }
    float mean = sum * (1.0f / 64.0f);
    float var  = fmaxf(sumsq * (1.0f / 64.0f) - mean * mean, 0.0f);
    mean_s[wv][lane] = mean;
    rstd_s[wv][lane] = rsqrtf(var + LN_EPS);
    __syncthreads();

#pragma unroll
    for (int it = 0; it < 16; ++it) {
        int idx = it * 64 + lane;
        int n = idx >> 4, k4 = idx & 15;
        if (n < nvalid) {
            float m = mean_s[wv][n], r = rstd_s[wv][n];
            float4 gg = g4[k4], bb = bt4[k4];
            float4 xx = x4[(i0 + n) * 16 + k4];
            int base = n * 65 + k4 * 4;
            float4 o;
            o.x = (slab[base]     - m) * r * gg.x + bb.x + xx.x;
            o.y = (slab[base + 1] - m) * r * gg.y + bb.y + xx.y;
            o.z = (slab[base + 2] - m) * r * gg.z + bb.z + xx.z;
            o.w = (slab[base + 3] - m) * r * gg.w + bb.w + xx.w;
            out4[(i0 + n) * 16 + k4] = o;
        }
    }
}

// ---------------------------------------------------------------------------
extern "C" void kernel_launch(void* const* d_in, const int* in_sizes, int n_in,
                              void* d_out, int out_size, void* d_ws, size_t ws_size,
                              hipStream_t stream) {
    const float* x   = (const float*)d_in[0];
    const int*   ei  = (const int*)  d_in[1];   // [2,E] flat: rows then cols
    const float* ew  = (const float*)d_in[2];
    const float* W   = (const float*)d_in[3];
    const float* b   = (const float*)d_in[4];
    const float* g   = (const float*)d_in[5];
    const float* bt  = (const float*)d_in[6];
    float* out = (float*)d_out;

    const int N = in_sizes[0] / 64;
    const int E = in_sizes[1] / 2;
    const int* rows = ei;
    const int* cols = ei + E;
    const int NB = (N + 1023) / 1024;

    // ws carve-up
    char* w8 = (char*)d_ws;
    int2*  meta   = (int2*)w8;                    w8 += (size_t)E * 8;
    float* deg    = (float*)w8;                   w8 += (size_t)N * 4;  // -> dis
    int*   counts = (int*)w8;                     w8 += (size_t)N * 4;  // -> cursor
    int*   rowptr = (int*)w8;                     w8 += (size_t)(N + 1) * 4;
    int*   bsums  = (int*)w8;                     w8 += (size_t)NB * 4;
    int*   boffs  = (int*)w8;

    k_init<<<(N + 255) / 256, 256, 0, stream>>>(deg, counts, N);
    k_deg_count<<<(E + 255) / 256, 256, 0, stream>>>(rows, ew, deg, counts, E);
    k_scan1<<<NB, 256, 0, stream>>>(counts, bsums, N);
    k_scan2<<<1, 64, 0, stream>>>(bsums, boffs, rowptr, NB, N);
    k_scan3<<<NB, 256, 0, stream>>>(counts, boffs, rowptr, counts /*cursor*/, deg, N);
    k_fill<<<(E + 255) / 256, 256, 0, stream>>>(rows, cols, ew, deg /*dis*/,
                                                rowptr, counts /*cursor*/, meta, E);
    long total = (long)N * 64;
    k_spmm_csr<<<(int)((total + 255) / 256), 256, 0, stream>>>(
        rowptr, meta, deg /*dis*/, x, out, N);

    int tiles = (N + 63) / 64;
    k_epilogue<<<(tiles + 3) / 4, 256, 0, stream>>>(
        (const float4*)x, W, b, (const float4*)g, (const float4*)bt, out, N);
}

// Round 3
// 265.471 us; speedup vs baseline: 1.5788x; 1.2697x over previous
//
#include <hip/hip_runtime.h>
#include <math.h>

#define DEG_EPS 1e-12f
#define LN_EPS  1e-5f

// ---------------------------------------------------------------------------
// ws layout (8-byte aligned first):
//   packed : N * 8   (bits [55:40] = edge count, bits [39:0] = sum(ew)*2^24)
//   meta   : E * 8   (int2 {col, bitcast(nw)})
//   ord    : E * 4   (within-row ordinal of each edge, from atomic return)
//   dis    : N * 4   (rsqrt(deg+eps))
//   rowptr : (N+1)*4
//   bsums  : NB * 4
//   boffs  : NB * 4
// ---------------------------------------------------------------------------

__global__ __launch_bounds__(256) void k_init(unsigned long long* __restrict__ packed,
                                              int N) {
    int i = blockIdx.x * blockDim.x + threadIdx.x;
    if (i < N) packed[i] = 0ULL;
}

// one 64-bit atomic per edge: count + fixed-point deg; return gives ordinal
__global__ __launch_bounds__(256) void k_count_deg(const int* __restrict__ rows,
                                                   const float* __restrict__ ew,
                                                   unsigned long long* __restrict__ packed,
                                                   unsigned* __restrict__ ord, int E) {
    int e = blockIdx.x * blockDim.x + threadIdx.x;
    if (e < E) {
        int r = rows[e];
        unsigned long long fx = (unsigned long long)__float2uint_rn(ew[e] * 16777216.0f);
        unsigned long long old = atomicAdd(&packed[r], (1ULL << 40) | fx);
        ord[e] = (unsigned)(old >> 40);
    }
}

// per-block (1024 rows) count reduction -> bsums
__global__ __launch_bounds__(256) void k_scan1(const unsigned long long* __restrict__ packed,
                                               int* __restrict__ bsums, int N) {
    __shared__ int sc[256];
    int t = threadIdx.x, b = blockIdx.x;
    int base = b * 1024 + t * 4;
    int s = 0;
#pragma unroll
    for (int k = 0; k < 4; ++k) {
        int i = base + k;
        if (i < N) s += (int)(packed[i] >> 40);
    }
    sc[t] = s; __syncthreads();
    for (int off = 128; off > 0; off >>= 1) {
        if (t < off) sc[t] += sc[t + off];
        __syncthreads();
    }
    if (t == 0) bsums[b] = sc[0];
}

// serial exclusive scan of block sums (NB ~ 98)
__global__ void k_scan2(const int* __restrict__ bsums, int* __restrict__ boffs,
                        int* __restrict__ rowptr, int NB, int N) {
    if (threadIdx.x == 0 && blockIdx.x == 0) {
        int run = 0;
        for (int b = 0; b < NB; ++b) { boffs[b] = run; run += bsums[b]; }
        rowptr[N] = run;   // == E
    }
}

// block scan -> rowptr (exclusive); dis = rsqrt(deg+eps) from packed low bits
__global__ __launch_bounds__(256) void k_scan3(const unsigned long long* __restrict__ packed,
                                               const int* __restrict__ boffs,
                                               int* __restrict__ rowptr,
                                               float* __restrict__ dis, int N) {
    __shared__ int sc[256];
    int t = threadIdx.x, b = blockIdx.x;
    int base = b * 1024 + t * 4;
    int c[4]; int s = 0;
#pragma unroll
    for (int k = 0; k < 4; ++k) {
        int i = base + k;
        unsigned long long p = (i < N) ? packed[i] : 0ULL;
        c[k] = (int)(p >> 40);
        s += c[k];
        if (i < N) {
            double deg = 1.0 + (double)(p & 0xFFFFFFFFFFULL) * (1.0 / 16777216.0);
            dis[i] = rsqrtf((float)deg + DEG_EPS);
        }
    }
    sc[t] = s; __syncthreads();
    int mySum = s;
    for (int off = 1; off < 256; off <<= 1) {
        int v = (t >= off) ? sc[t - off] : 0;
        __syncthreads();
        sc[t] += v;
        __syncthreads();
    }
    int run = sc[t] - mySum + boffs[b];
#pragma unroll
    for (int k = 0; k < 4; ++k) {
        int i = base + k;
        if (i < N) rowptr[i] = run;
        run += c[k];
    }
}

// fill CSR — atomic-free: slot = rowptr[r] + ord[e]
__global__ __launch_bounds__(256) void k_fill(const int* __restrict__ rows,
                                              const int* __restrict__ cols,
                                              const float* __restrict__ ew,
                                              const unsigned* __restrict__ ord,
                                              const float* __restrict__ dis,
                                              const int* __restrict__ rowptr,
                                              int2* __restrict__ meta, int E) {
    int e = blockIdx.x * blockDim.x + threadIdx.x;
    if (e < E) {
        int r = rows[e], c = cols[e];
        float nw = ew[e] * dis[r] * dis[c];
        int slot = rowptr[r] + (int)ord[e];
        meta[slot] = make_int2(c, __float_as_int(nw));
    }
}

// SpMM gather: one wave per row, lane = feature. No atomics.
__global__ __launch_bounds__(256) void k_spmm_csr(const int* __restrict__ rowptr,
                                                  const int2* __restrict__ meta,
                                                  const float* __restrict__ dis,
                                                  const float* __restrict__ x,
                                                  float* __restrict__ h, int N) {
    int t = blockIdx.x * blockDim.x + threadIdx.x;
    int row = t >> 6;
    if (row >= N) return;
    int lane = t & 63;

    float s = dis[row];                       // wave-uniform
    float acc = x[row * 64 + lane] * (s * s); // self loop: x / (deg+eps)

    int start = rowptr[row], end = rowptr[row + 1];
    for (int base = start; base < end; base += 64) {
        int rem = end - base;
        int cnt = rem < 64 ? rem : 64;
        int2 m = make_int2(0, 0);
        if (lane < rem) m = meta[base + lane];   // 64 edges in one coalesced load
        int j = 0;
        for (; j + 4 <= cnt; j += 4) {
            int   c0 = __shfl(m.x, j + 0, 64);
            float w0 = __int_as_float(__shfl(m.y, j + 0, 64));
            int   c1 = __shfl(m.x, j + 1, 64);
            float w1 = __int_as_float(__shfl(m.y, j + 1, 64));
            int   c2 = __shfl(m.x, j + 2, 64);
            float w2 = __int_as_float(__shfl(m.y, j + 2, 64));
            int   c3 = __shfl(m.x, j + 3, 64);
            float w3 = __int_as_float(__shfl(m.y, j + 3, 64));
            float v0 = x[c0 * 64 + lane];
            float v1 = x[c1 * 64 + lane];
            float v2 = x[c2 * 64 + lane];
            float v3 = x[c3 * 64 + lane];
            acc = fmaf(v0, w0, acc);
            acc = fmaf(v1, w1, acc);
            acc = fmaf(v2, w2, acc);
            acc = fmaf(v3, w3, acc);
        }
        for (; j < cnt; ++j) {
            int   c = __shfl(m.x, j, 64);
            float w = __int_as_float(__shfl(m.y, j, 64));
            acc = fmaf(x[c * 64 + lane], w, acc);
        }
    }
    h[row * 64 + lane] = acc;
}

// ---------------------------------------------------------------------------
// Epilogue: y = gelu(h@W^T + b); LN(y)*gamma+beta + x  (in-place on d_out)
// ---------------------------------------------------------------------------
__global__ __launch_bounds__(256) void k_epilogue(
    const float4* __restrict__ x4, const float* __restrict__ W,
    const float* __restrict__ bias, const float4* __restrict__ g4,
    const float4* __restrict__ bt4, float* __restrict__ h, int N)
{
    __shared__ float slab_s[4][64 * 65];
    __shared__ float mean_s[4][64];
    __shared__ float rstd_s[4][64];
    const int wv   = threadIdx.x >> 6;
    const int lane = threadIdx.x & 63;
    float* slab = slab_s[wv];
    const int i0 = (blockIdx.x * 4 + wv) * 64;
    const int nvalid = (i0 < N) ? min(64, N - i0) : 0;
    const float4* h4 = (const float4*)h;
    float4* out4 = (float4*)h;

#pragma unroll
    for (int it = 0; it < 16; ++it) {
        int idx = it * 64 + lane;
        int n = idx >> 4, k4 = idx & 15;
        if (n < nvalid) {
            float4 v = h4[(i0 + n) * 16 + k4];
            int base = n * 65 + k4 * 4;
            slab[base] = v.x; slab[base + 1] = v.y;
            slab[base + 2] = v.z; slab[base + 3] = v.w;
        }
    }
    __syncthreads();

    float hr[64];
#pragma unroll
    for (int k = 0; k < 64; ++k) hr[k] = slab[lane * 65 + k];
    __syncthreads();

    float sum = 0.f, sumsq = 0.f;
    for (int j = 0; j < 64; ++j) {
        float a = bias[j];
#pragma unroll
        for (int k = 0; k < 64; ++k)
            a = fmaf(hr[k], W[j * 64 + k], a);
        a = 0.5f * a * (1.0f + erff(a * 0.70710678118654752f));
        sum += a; sumsq += a * a;
        slab[lane * 65 + j] = a;
    }
    float mean = sum * (1.0f / 64.0f);
    float var  = fmaxf(sumsq * (1.0f / 64.0f) - mean * mean, 0.0f);
    mean_s[wv][lane] = mean;
    rstd_s[wv][lane] = rsqrtf(var + LN_EPS);
    __syncthreads();

#pragma unroll
    for (int it = 0; it < 16; ++it) {
        int idx = it * 64 + lane;
        int n = idx >> 4, k4 = idx & 15;
        if (n < nvalid) {
            float m = mean_s[wv][n], r = rstd_s[wv][n];
            float4 gg = g4[k4], bb = bt4[k4];
            float4 xx = x4[(i0 + n) * 16 + k4];
            int base = n * 65 + k4 * 4;
            float4 o;
            o.x = (slab[base]     - m) * r * gg.x + bb.x + xx.x;
            o.y = (slab[base + 1] - m) * r * gg.y + bb.y + xx.y;
            o.z = (slab[base + 2] - m) * r * gg.z + bb.z + xx.z;
            o.w = (slab[base + 3] - m) * r * gg.w + bb.w + xx.w;
            out4[(i0 + n) * 16 + k4] = o;
        }
    }
}

// ---------------------------------------------------------------------------
extern "C" void kernel_launch(void* const* d_in, const int* in_sizes, int n_in,
                              void* d_out, int out_size, void* d_ws, size_t ws_size,
                              hipStream_t stream) {
    const float* x   = (const float*)d_in[0];
    const int*   ei  = (const int*)  d_in[1];   // [2,E] flat: rows then cols
    const float* ew  = (const float*)d_in[2];
    const float* W   = (const float*)d_in[3];
    const float* b   = (const float*)d_in[4];
    const float* g   = (const float*)d_in[5];
    const float* bt  = (const float*)d_in[6];
    float* out = (float*)d_out;

    const int N = in_sizes[0] / 64;
    const int E = in_sizes[1] / 2;
    const int* rows = ei;
    const int* cols = ei + E;
    const int NB = (N + 1023) / 1024;

    // ws carve-up (8-byte aligned members first)
    char* w8 = (char*)d_ws;
    unsigned long long* packed = (unsigned long long*)w8; w8 += (size_t)N * 8;
    int2*     meta   = (int2*)w8;                         w8 += (size_t)E * 8;
    unsigned* ord    = (unsigned*)w8;                     w8 += (size_t)E * 4;
    float*    dis    = (float*)w8;                        w8 += (size_t)N * 4;
    int*      rowptr = (int*)w8;                          w8 += (size_t)(N + 1) * 4;
    int*      bsums  = (int*)w8;                          w8 += (size_t)NB * 4;
    int*      boffs  = (int*)w8;

    k_init<<<(N + 255) / 256, 256, 0, stream>>>(packed, N);
    k_count_deg<<<(E + 255) / 256, 256, 0, stream>>>(rows, ew, packed, ord, E);
    k_scan1<<<NB, 256, 0, stream>>>(packed, bsums, N);
    k_scan2<<<1, 64, 0, stream>>>(bsums, boffs, rowptr, NB, N);
    k_scan3<<<NB, 256, 0, stream>>>(packed, boffs, rowptr, dis, N);
    k_fill<<<(E + 255) / 256, 256, 0, stream>>>(rows, cols, ew, ord, dis,
                                                rowptr, meta, E);
    long total = (long)N * 64;
    k_spmm_csr<<<(int)((total + 255) / 256), 256, 0, stream>>>(
        rowptr, meta, dis, x, out, N);

    int tiles = (N + 63) / 64;
    k_epilogue<<<(tiles + 3) / 4, 256, 0, stream>>>(
        (const float4*)x, W, b, (const float4*)g, (const float4*)bt, out, N);
}

// Round 4
// 252.810 us; speedup vs baseline: 1.6579x; 1.0501x over previous
//
#include <hip/hip_runtime.h>
#include <math.h>

#define DEG_EPS 1e-12f
#define LN_EPS  1e-5f

// ---------------------------------------------------------------------------
// ws layout (8-byte aligned first):
//   packed : N * 8   (bits [55:40] = edge count, bits [39:0] = sum(ew)*2^24)
//   meta   : E * 8   (int2 {col, bitcast(nw)})
//   ord    : E * 4   (within-row ordinal of each edge, from atomic return)
//   dis    : N * 4   (rsqrt(deg+eps))
//   rowptr : (N+1)*4
//   bsums  : NB * 4
//   boffs  : NB * 4
// ---------------------------------------------------------------------------

__global__ __launch_bounds__(256) void k_init(unsigned long long* __restrict__ packed,
                                              int N) {
    int i = blockIdx.x * blockDim.x + threadIdx.x;
    if (i < N) packed[i] = 0ULL;
}

// one 64-bit atomic per edge: count + fixed-point deg; return gives ordinal
__global__ __launch_bounds__(256) void k_count_deg(const int* __restrict__ rows,
                                                   const float* __restrict__ ew,
                                                   unsigned long long* __restrict__ packed,
                                                   unsigned* __restrict__ ord, int E) {
    int e = blockIdx.x * blockDim.x + threadIdx.x;
    if (e < E) {
        int r = rows[e];
        unsigned long long fx = (unsigned long long)__float2uint_rn(ew[e] * 16777216.0f);
        unsigned long long old = atomicAdd(&packed[r], (1ULL << 40) | fx);
        ord[e] = (unsigned)(old >> 40);
    }
}

// per-block (1024 rows) count reduction -> bsums
__global__ __launch_bounds__(256) void k_scan1(const unsigned long long* __restrict__ packed,
                                               int* __restrict__ bsums, int N) {
    __shared__ int sc[256];
    int t = threadIdx.x, b = blockIdx.x;
    int base = b * 1024 + t * 4;
    int s = 0;
#pragma unroll
    for (int k = 0; k < 4; ++k) {
        int i = base + k;
        if (i < N) s += (int)(packed[i] >> 40);
    }
    sc[t] = s; __syncthreads();
    for (int off = 128; off > 0; off >>= 1) {
        if (t < off) sc[t] += sc[t + off];
        __syncthreads();
    }
    if (t == 0) bsums[b] = sc[0];
}

// serial exclusive scan of block sums (NB ~ 98)
__global__ void k_scan2(const int* __restrict__ bsums, int* __restrict__ boffs,
                        int* __restrict__ rowptr, int NB, int N) {
    if (threadIdx.x == 0 && blockIdx.x == 0) {
        int run = 0;
        for (int b = 0; b < NB; ++b) { boffs[b] = run; run += bsums[b]; }
        rowptr[N] = run;   // == E
    }
}

// block scan -> rowptr (exclusive); dis = rsqrt(deg+eps) from packed low bits
__global__ __launch_bounds__(256) void k_scan3(const unsigned long long* __restrict__ packed,
                                               const int* __restrict__ boffs,
                                               int* __restrict__ rowptr,
                                               float* __restrict__ dis, int N) {
    __shared__ int sc[256];
    int t = threadIdx.x, b = blockIdx.x;
    int base = b * 1024 + t * 4;
    int c[4]; int s = 0;
#pragma unroll
    for (int k = 0; k < 4; ++k) {
        int i = base + k;
        unsigned long long p = (i < N) ? packed[i] : 0ULL;
        c[k] = (int)(p >> 40);
        s += c[k];
        if (i < N) {
            double deg = 1.0 + (double)(p & 0xFFFFFFFFFFULL) * (1.0 / 16777216.0);
            dis[i] = rsqrtf((float)deg + DEG_EPS);
        }
    }
    sc[t] = s; __syncthreads();
    int mySum = s;
    for (int off = 1; off < 256; off <<= 1) {
        int v = (t >= off) ? sc[t - off] : 0;
        __syncthreads();
        sc[t] += v;
        __syncthreads();
    }
    int run = sc[t] - mySum + boffs[b];
#pragma unroll
    for (int k = 0; k < 4; ++k) {
        int i = base + k;
        if (i < N) rowptr[i] = run;
        run += c[k];
    }
}

// fill CSR — atomic-free: slot = rowptr[r] + ord[e]
__global__ __launch_bounds__(256) void k_fill(const int* __restrict__ rows,
                                              const int* __restrict__ cols,
                                              const float* __restrict__ ew,
                                              const unsigned* __restrict__ ord,
                                              const float* __restrict__ dis,
                                              const int* __restrict__ rowptr,
                                              int2* __restrict__ meta, int E) {
    int e = blockIdx.x * blockDim.x + threadIdx.x;
    if (e < E) {
        int r = rows[e], c = cols[e];
        float nw = ew[e] * dis[r] * dis[c];
        int slot = rowptr[r] + (int)ord[e];
        meta[slot] = make_int2(c, __float_as_int(nw));
    }
}

// SpMM gather: one wave per row, lane = feature. No atomics.
__global__ __launch_bounds__(256) void k_spmm_csr(const int* __restrict__ rowptr,
                                                  const int2* __restrict__ meta,
                                                  const float* __restrict__ dis,
                                                  const float* __restrict__ x,
                                                  float* __restrict__ h, int N) {
    int t = blockIdx.x * blockDim.x + threadIdx.x;
    int row = t >> 6;
    if (row >= N) return;
    int lane = t & 63;

    float s = dis[row];                       // wave-uniform
    float acc = x[row * 64 + lane] * (s * s); // self loop: x / (deg+eps)

    int start = rowptr[row], end = rowptr[row + 1];
    for (int base = start; base < end; base += 64) {
        int rem = end - base;
        int cnt = rem < 64 ? rem : 64;
        int2 m = make_int2(0, 0);
        if (lane < rem) m = meta[base + lane];   // 64 edges in one coalesced load
        int j = 0;
        for (; j + 4 <= cnt; j += 4) {
            int   c0 = __shfl(m.x, j + 0, 64);
            float w0 = __int_as_float(__shfl(m.y, j + 0, 64));
            int   c1 = __shfl(m.x, j + 1, 64);
            float w1 = __int_as_float(__shfl(m.y, j + 1, 64));
            int   c2 = __shfl(m.x, j + 2, 64);
            float w2 = __int_as_float(__shfl(m.y, j + 2, 64));
            int   c3 = __shfl(m.x, j + 3, 64);
            float w3 = __int_as_float(__shfl(m.y, j + 3, 64));
            float v0 = x[c0 * 64 + lane];
            float v1 = x[c1 * 64 + lane];
            float v2 = x[c2 * 64 + lane];
            float v3 = x[c3 * 64 + lane];
            acc = fmaf(v0, w0, acc);
            acc = fmaf(v1, w1, acc);
            acc = fmaf(v2, w2, acc);
            acc = fmaf(v3, w3, acc);
        }
        for (; j < cnt; ++j) {
            int   c = __shfl(m.x, j, 64);
            float w = __int_as_float(__shfl(m.y, j, 64));
            acc = fmaf(x[c * 64 + lane], w, acc);
        }
    }
    h[row * 64 + lane] = acc;
}

// ---------------------------------------------------------------------------
// Epilogue v2: y = gelu(h@W^T + b); LN(y)*gamma+beta + x  (in-place on d_out)
//   - W staged in LDS once per block (float4 broadcast reads)
//   - K chunked by 16: slab 64x17 per region (conflict-free transpose reads)
//   - 2 waves per 64-node tile split the 64 output features (32 each);
//     LN stats combined via tiny LDS exchange -> 2x wave parallelism
// ---------------------------------------------------------------------------
__global__ __launch_bounds__(256) void k_epilogue(
    const float4* __restrict__ x4, const float4* __restrict__ W4,
    const float* __restrict__ bias, const float4* __restrict__ g4,
    const float4* __restrict__ bt4, float* __restrict__ h, int N)
{
    __shared__ float4 Wl4[1024];          // W row-major: Wl4[j*16 + kq]
    __shared__ float  slab[4][64 * 17];   // input: region 2t; output: region wv
    __shared__ float  psum[2][2][64];
    __shared__ float  psq[2][2][64];

    const int tid  = threadIdx.x;
    const int wv   = tid >> 6;
    const int lane = tid & 63;
    const int t    = wv >> 1;   // tile in block (0..1)
    const int p    = wv & 1;    // output-feature half (0..1)

    // stage W: 1024 float4 over 256 threads
#pragma unroll
    for (int i = 0; i < 4; ++i)
        Wl4[i * 256 + tid] = W4[i * 256 + tid];

    const int i0 = (blockIdx.x * 2 + t) * 64;
    const int nvalid = (i0 < N) ? min(64, N - i0) : 0;
    const float4* h4 = (const float4*)h;
    float4* out4 = (float4*)h;
    float* islab = slab[2 * t];

    float y[32];
#pragma unroll
    for (int j = 0; j < 32; ++j) y[j] = 0.f;

    for (int c = 0; c < 4; ++c) {
        __syncthreads();
        // cooperative chunk load: 2 waves x 2 iters cover 64 nodes x 4 float4
#pragma unroll
        for (int it = 0; it < 2; ++it) {
            int idx = (p * 2 + it) * 64 + lane;
            int n = idx >> 2, q = idx & 3;
            if (n < nvalid) {
                float4 v = h4[(size_t)(i0 + n) * 16 + c * 4 + q];
                int b = n * 17 + q * 4;
                islab[b] = v.x; islab[b + 1] = v.y;
                islab[b + 2] = v.z; islab[b + 3] = v.w;
            }
        }
        __syncthreads();
        float hr[16];
#pragma unroll
        for (int k = 0; k < 16; ++k) hr[k] = islab[lane * 17 + k];  // conflict-free
#pragma unroll
        for (int j = 0; j < 32; ++j) {
            int base = (p * 32 + j) * 16 + c * 4;     // wave-uniform -> broadcast
            float4 w0 = Wl4[base + 0];
            float4 w1 = Wl4[base + 1];
            float4 w2 = Wl4[base + 2];
            float4 w3 = Wl4[base + 3];
            float acc = y[j];
            acc = fmaf(hr[0],  w0.x, acc); acc = fmaf(hr[1],  w0.y, acc);
            acc = fmaf(hr[2],  w0.z, acc); acc = fmaf(hr[3],  w0.w, acc);
            acc = fmaf(hr[4],  w1.x, acc); acc = fmaf(hr[5],  w1.y, acc);
            acc = fmaf(hr[6],  w1.z, acc); acc = fmaf(hr[7],  w1.w, acc);
            acc = fmaf(hr[8],  w2.x, acc); acc = fmaf(hr[9],  w2.y, acc);
            acc = fmaf(hr[10], w2.z, acc); acc = fmaf(hr[11], w2.w, acc);
            acc = fmaf(hr[12], w3.x, acc); acc = fmaf(hr[13], w3.y, acc);
            acc = fmaf(hr[14], w3.z, acc); acc = fmaf(hr[15], w3.w, acc);
            y[j] = acc;
        }
    }

    // gelu + per-half LN stats (lane owns its node)
    float sum = 0.f, ssq = 0.f;
#pragma unroll
    for (int j = 0; j < 32; ++j) {
        float a = y[j] + bias[p * 32 + j];
        a = 0.5f * a * (1.0f + erff(a * 0.70710678118654752f));
        y[j] = a;
        sum += a; ssq += a * a;
    }
    psum[t][p][lane] = sum;
    psq[t][p][lane]  = ssq;
    __syncthreads();
    float S = psum[t][0][lane] + psum[t][1][lane];
    float Q = psq[t][0][lane]  + psq[t][1][lane];
    float m = S * (1.0f / 64.0f);
    float var = fmaxf(Q * (1.0f / 64.0f) - m * m, 0.0f);
    float rs = rsqrtf(var + LN_EPS);

    // output: two 16-feature chunks through per-wave slab region
    float* oslab = slab[wv];
#pragma unroll
    for (int c2 = 0; c2 < 2; ++c2) {
        __syncthreads();
#pragma unroll
        for (int k = 0; k < 16; ++k)
            oslab[lane * 17 + k] = (y[c2 * 16 + k] - m) * rs;
        __syncthreads();
#pragma unroll
        for (int it = 0; it < 4; ++it) {
            int idx = it * 64 + lane;
            int n = idx >> 2, q = idx & 3;
            if (n < nvalid) {
                int jq = p * 8 + c2 * 4 + q;          // float4 index within 16
                float4 gg = g4[jq], bb = bt4[jq];
                float4 xx = x4[(size_t)(i0 + n) * 16 + jq];
                int b = n * 17 + q * 4;
                float4 o;
                o.x = oslab[b]     * gg.x + bb.x + xx.x;
                o.y = oslab[b + 1] * gg.y + bb.y + xx.y;
                o.z = oslab[b + 2] * gg.z + bb.z + xx.z;
                o.w = oslab[b + 3] * gg.w + bb.w + xx.w;
                out4[(size_t)(i0 + n) * 16 + jq] = o;
            }
        }
    }
}

// ---------------------------------------------------------------------------
extern "C" void kernel_launch(void* const* d_in, const int* in_sizes, int n_in,
                              void* d_out, int out_size, void* d_ws, size_t ws_size,
                              hipStream_t stream) {
    const float* x   = (const float*)d_in[0];
    const int*   ei  = (const int*)  d_in[1];   // [2,E] flat: rows then cols
    const float* ew  = (const float*)d_in[2];
    const float* W   = (const float*)d_in[3];
    const float* b   = (const float*)d_in[4];
    const float* g   = (const float*)d_in[5];
    const float* bt  = (const float*)d_in[6];
    float* out = (float*)d_out;

    const int N = in_sizes[0] / 64;
    const int E = in_sizes[1] / 2;
    const int* rows = ei;
    const int* cols = ei + E;
    const int NB = (N + 1023) / 1024;

    // ws carve-up (8-byte aligned members first)
    char* w8 = (char*)d_ws;
    unsigned long long* packed = (unsigned long long*)w8; w8 += (size_t)N * 8;
    int2*     meta   = (int2*)w8;                         w8 += (size_t)E * 8;
    unsigned* ord    = (unsigned*)w8;                     w8 += (size_t)E * 4;
    float*    dis    = (float*)w8;                        w8 += (size_t)N * 4;
    int*      rowptr = (int*)w8;                          w8 += (size_t)(N + 1) * 4;
    int*      bsums  = (int*)w8;                          w8 += (size_t)NB * 4;
    int*      boffs  = (int*)w8;

    k_init<<<(N + 255) / 256, 256, 0, stream>>>(packed, N);
    k_count_deg<<<(E + 255) / 256, 256, 0, stream>>>(rows, ew, packed, ord, E);
    k_scan1<<<NB, 256, 0, stream>>>(packed, bsums, N);
    k_scan2<<<1, 64, 0, stream>>>(bsums, boffs, rowptr, NB, N);
    k_scan3<<<NB, 256, 0, stream>>>(packed, boffs, rowptr, dis, N);
    k_fill<<<(E + 255) / 256, 256, 0, stream>>>(rows, cols, ew, ord, dis,
                                                rowptr, meta, E);
    long total = (long)N * 64;
    k_spmm_csr<<<(int)((total + 255) / 256), 256, 0, stream>>>(
        rowptr, meta, dis, x, out, N);

    int tiles = (N + 63) / 64;         // 64-node tiles
    int eblocks = (tiles + 1) / 2;     // 2 tiles per block (2 waves each)
    k_epilogue<<<eblocks, 256, 0, stream>>>(
        (const float4*)x, (const float4*)W, b, (const float4*)g,
        (const float4*)bt, out, N);
}